// Round 14
// baseline (237.867 us; speedup 1.0000x reference)
//
#include <hip/hip_runtime.h>

typedef unsigned short u16;
typedef unsigned int u32;
typedef __attribute__((ext_vector_type(8))) short bf16x8;   // 8 bf16 in 4 VGPRs
typedef __attribute__((ext_vector_type(4))) float f32x4;

// ---------- bf16 helpers (RNE) ----------
__device__ __forceinline__ u16 f2bf(float f) {
  union { float f; u32 u; } v; v.f = f;
  u32 u = v.u;
  return (u16)((u + 0x7FFFu + ((u >> 16) & 1u)) >> 16);
}
__device__ __forceinline__ float bf2f(u16 s) {
  union { u32 u; float f; } v; v.u = ((u32)s) << 16;
  return v.f;
}

// ---------- async global->LDS (16B per lane) ----------
__device__ __forceinline__ void async16(const void* g, void* l) {
  __builtin_amdgcn_global_load_lds(
      (__attribute__((address_space(1))) void*)g,
      (__attribute__((address_space(3))) void*)l, 16, 0, 0);
}

#define VM4  asm volatile("s_waitcnt vmcnt(4)" ::: "memory")
#define VM0  asm volatile("s_waitcnt vmcnt(0)" ::: "memory")
#define LG0  asm volatile("s_waitcnt lgkmcnt(0)" ::: "memory")
#define BARX do { asm volatile("" ::: "memory"); __builtin_amdgcn_s_barrier(); \
                  asm volatile("" ::: "memory"); } while (0)

// ---------- prep1: fused {4x weight transpose+cast, x cast, trig table} ----------
__global__ void prep1_kernel(const float* __restrict__ x,
                             const float* __restrict__ W0, const float* __restrict__ W1,
                             const float* __restrict__ W2, const float* __restrict__ W3,
                             const float* __restrict__ freqs,
                             u16* __restrict__ xbf, u16* __restrict__ wqkvT,
                             u16* __restrict__ woT,
                             float* __restrict__ ct, float* __restrict__ st) {
  __shared__ float tile[64][33];
  const int bid = blockIdx.x;
  const int tid = threadIdx.x;
  if (bid < 8192) {
    const int z = bid >> 11;
    const float* in = z == 0 ? W0 : z == 1 ? W1 : z == 2 ? W2 : W3;
    u16* out = z == 3 ? woT : wqkvT + (size_t)z * 4194304;
    const int local = bid & 2047;
    const int c0 = (local & 63) * 32;
    const int r0 = (local >> 6) * 64;
#pragma unroll
    for (int it = 0; it < 8; ++it) {
      int idx = it * 256 + tid;
      int row = idx >> 5, col = idx & 31;
      tile[row][col] = in[(size_t)(r0 + row) * 2048 + c0 + col];
    }
    __syncthreads();
#pragma unroll
    for (int it = 0; it < 4; ++it) {
      int idx = it * 256 + tid;
      int orow = idx >> 5, oc2 = idx & 31;
      u32 v = (u32)f2bf(tile[2 * oc2][orow]) | ((u32)f2bf(tile[2 * oc2 + 1][orow]) << 16);
      *(u32*)(out + (size_t)(c0 + orow) * 2048 + r0 + 2 * oc2) = v;
    }
  } else if (bid < 16384) {
    int i = (bid - 8192) * 256 + tid;      // < 2097152
    float4 v = ((const float4*)x)[i];
    ushort4 o;
    o.x = f2bf(v.x); o.y = f2bf(v.y); o.z = f2bf(v.z); o.w = f2bf(v.w);
    ((ushort4*)xbf)[i] = o;
  } else {
    int i = (bid - 16384) * 256 + tid;     // < 262144
    float f = freqs[i];
    ct[i] = cosf(f); st[i] = sinf(f);
  }
}

// ---------- 8-phase 256x256 QKV GEMM, race-corrected staging schedule ----------
// BM=BN=256, BK=64, 512 thr (8 waves 2Mx4N, per-wave 128x64 C). 2-stage LDS
// dbuf (128KB, 1 block/CU). Iteration = 2 K-tiles = 8 phases.
// READ SPANS (key correction vs r13): each LDA/LDB quadrant read touches BOTH
// staging halves (wm=1 / wn>=2 waves read rows 128..255). Slot-free table:
//   s0.B free after P2; s0.A free after P3; s1.B free after P6; s1.A after P7.
// Staging (2 loads/phase): P1:s1.Ah0(t+1) P2:s1.Ah1(t+1) P3:s0.Bh0(t+2)
//   P4:s0.Bh1(t+2) P5:s0.Ah0(t+2) P6:s0.Ah1(t+2) P7:s1.Bh0(t+3) P8:s1.Bh1(t+3)
// Gates: VM4 at P4 (drains prevP7..P2 = s1 tile's 8 loads before P5 reads) and
// VM4 at P8 (drains P3..P6 = s0 tile's 8 loads before next P1); last iteration
// VM0 at P4. Prologue stages s0-tile0 full + s1.B-tile1 then VM4 (= invariant).
// Column remap col(f) = (wn>>1)*128 + (f>>1)*64 + (wn&1)*32 + (f&1)*16 + c puts
// RoPE pairs (d, d+64) in (acc[m][n], acc[m][n+2]) of one thread.
__launch_bounds__(512, 1)
__global__ void gemm256_qkv_kernel(const u16* __restrict__ A, const u16* __restrict__ Bt,
                                   u16* __restrict__ Q, u16* __restrict__ Kp,
                                   u16* __restrict__ VT2,
                                   const float* __restrict__ ct, const float* __restrict__ st) {
  const int K = 2048;
  __shared__ __align__(16) char smem[131072];   // stage s: A at s*65536, B at +32768
  const int tid = threadIdx.x;
  const int lane = tid & 63, wave = tid >> 6;
  const int wm = wave >> 2, wn = wave & 3;
  const int g = lane >> 4, c = lane & 15;
  const int brow = blockIdx.y * 256;
  const int bcol = blockIdx.x * 256;

  // staging addresses: linear LDS dest, inverse-swizzled global source
  int sp[2][2], aso[2][2], bso[2][2];
#pragma unroll
  for (int h = 0; h < 2; ++h)
#pragma unroll
    for (int cc = 0; cc < 2; ++cc) {
      int p = h * 16384 + cc * 8192 + tid * 16;   // byte within 32KB matrix region
      int row = p >> 7;                            // 0..255
      int colb = (p & 127) ^ ((row & 7) << 4);
      sp[h][cc] = p;
      aso[h][cc] = (brow + row) * K + (colb >> 1);
      bso[h][cc] = (bcol + row) * K + (colb >> 1);
    }
  auto stA = [&](int s, int h, int kt) {
#pragma unroll
    for (int cc = 0; cc < 2; ++cc)
      async16(A + aso[h][cc] + kt * 64, smem + s * 65536 + sp[h][cc]);
  };
  auto stB = [&](int s, int h, int kt) {
#pragma unroll
    for (int cc = 0; cc < 2; ++cc)
      async16(Bt + bso[h][cc] + kt * 64, smem + s * 65536 + 32768 + sp[h][cc]);
  };

  f32x4 acc[8][4];
#pragma unroll
  for (int m = 0; m < 8; ++m)
#pragma unroll
    for (int n = 0; n < 4; ++n) acc[m][n] = (f32x4){0.f, 0.f, 0.f, 0.f};
  bf16x8 aF[4][2], bF[4][2];

  auto LDA = [&](int s, int mh) {
#pragma unroll
    for (int mm = 0; mm < 4; ++mm) {
      int row = wm * 128 + mh * 64 + mm * 16 + c;
      int sw = (row & 7) << 4;
      const char* base = smem + s * 65536 + (row << 7);
#pragma unroll
      for (int kk = 0; kk < 2; ++kk)
        aF[mm][kk] = *(const bf16x8*)(base + ((kk * 64 + (g << 4)) ^ sw));
    }
  };
  auto LDB = [&](int s, int np) {
#pragma unroll
    for (int nn = 0; nn < 2; ++nn) {
      int row = (wn >> 1) * 128 + np * 64 + (wn & 1) * 32 + nn * 16 + c;
      int sw = (row & 7) << 4;
      const char* base = smem + s * 65536 + 32768 + (row << 7);
#pragma unroll
      for (int kk = 0; kk < 2; ++kk)
        bF[np * 2 + nn][kk] = *(const bf16x8*)(base + ((kk * 64 + (g << 4)) ^ sw));
    }
  };
  auto MF = [&](int mb, int np) {
    __builtin_amdgcn_s_setprio(1);
#pragma unroll
    for (int kk = 0; kk < 2; ++kk)
#pragma unroll
      for (int mm = 0; mm < 4; ++mm)
#pragma unroll
        for (int nn = 0; nn < 2; ++nn)
          acc[mb + mm][np * 2 + nn] = __builtin_amdgcn_mfma_f32_16x16x32_bf16(
              aF[mm][kk], bF[np * 2 + nn][kk], acc[mb + mm][np * 2 + nn], 0, 0, 0);
    __builtin_amdgcn_s_setprio(0);
  };

  // prologue: s0 = tile0 full (8 loads), then s1.B = tile1 (4 loads); VM4
  // leaves only s1.B outstanding -> steady-state invariant at P1 entry.
  stA(0, 0, 0); stA(0, 1, 0); stB(0, 0, 0); stB(0, 1, 0);
  stB(1, 0, 1); stB(1, 1, 1);
  VM4;
  BARX;

  const int NT = 32;
#pragma unroll 1
  for (int i = 0; i < 16; ++i) {
    const int t0 = 2 * i;
    const bool g2 = (t0 + 2) < NT, g3 = (t0 + 3) < NT;
    // P1: read s0{A-q0, B-np0}; stage s1.Ah0(t0+1)  [s1.A free since prev P7]
    LDA(0, 0); LDB(0, 0);
    stA(1, 0, t0 + 1);
    BARX; LG0; MF(0, 0); BARX;
    // P2: read s0.B-np1; stage s1.Ah1(t0+1)
    LDB(0, 1);
    stA(1, 1, t0 + 1);
    BARX; LG0; MF(0, 1); BARX;
    // P3: read s0.A-q1; stage s0.Bh0(t0+2)  [s0.B free after P2]
    LDA(0, 1);
    if (g2) stB(0, 0, t0 + 2);
    BARX; LG0; MF(4, 0); BARX;
    // P4: stage s0.Bh1(t0+2); gate s1-tile(t0+1) loads for P5..P7 reads
    if (g2) { stB(0, 1, t0 + 2); VM4; } else { VM0; }
    BARX; MF(4, 1); BARX;
    // P5: read s1{A-q0, B-np0}; stage s0.Ah0(t0+2)  [s0.A free after P3]
    LDA(1, 0); LDB(1, 0);
    if (g2) stA(0, 0, t0 + 2);
    BARX; LG0; MF(0, 0); BARX;
    // P6: read s1.B-np1; stage s0.Ah1(t0+2)
    LDB(1, 1);
    if (g2) stA(0, 1, t0 + 2);
    BARX; LG0; MF(0, 1); BARX;
    // P7: read s1.A-q1; stage s1.Bh0(t0+3)  [s1.B free after P6]
    LDA(1, 1);
    if (g3) stB(1, 0, t0 + 3);
    BARX; LG0; MF(4, 0); BARX;
    // P8: stage s1.Bh1(t0+3); gate s0-tile(t0+2) loads for next P1..P3 reads
    if (g3) { stB(1, 1, t0 + 3); VM4; } else { VM0; }
    BARX; MF(4, 1); BARX;
  }

  // ---- fused epilogue ----
  const int sel = bcol >> 11;                  // 0=q 1=k 2=v (block-uniform)
  if (sel < 2) {
    const int hh = ((bcol & 2047) >> 7) + (wn >> 1);
#pragma unroll
    for (int mf = 0; mf < 8; ++mf)
#pragma unroll
      for (int r = 0; r < 4; ++r) {
        const int t = brow + wm * 128 + mf * 16 + g * 4 + r;
        const int tb = t * 64;
#pragma unroll
        for (int n = 0; n < 2; ++n) {
          const int d = (wn & 1) * 32 + (n << 4) + c;   // 0..63
          float cv = ct[tb + d], sv = st[tb + d];
          float a = acc[mf][n][r], b = acc[mf][n + 2][r];
          u16 lo = f2bf(a * cv - b * sv);
          u16 hi = f2bf(b * cv + a * sv);
          if (sel == 0) {
            u16* qd = Q + (size_t)t * 2048 + hh * 128 + d;
            qd[0] = lo; qd[64] = hi;
          } else {
            u16* kd = Kp + ((size_t)hh * 4096 + t) * 128 + d;
            kd[0] = lo; kd[64] = hi;
          }
        }
      }
  } else {
    u16* eph = (u16*)smem;                      // [128][264] bf16 bounce
    const int hh0 = (bcol & 2047) >> 7;
#pragma unroll
    for (int half = 0; half < 2; ++half) {
      BARX;
      if (wm == half) {
#pragma unroll
        for (int mf = 0; mf < 8; ++mf)
#pragma unroll
          for (int n = 0; n < 4; ++n)
#pragma unroll
            for (int r = 0; r < 4; ++r) {
              int lr = mf * 16 + g * 4 + r;                              // 0..127
              int lc = (wn >> 1) * 128 + ((n >> 1) & 1) * 64 + (wn & 1) * 32 + (n & 1) * 16 + c;
              eph[lr * 264 + lc] = f2bf(acc[mf][n][r]);
            }
      }
      BARX;
      const int rowbase = brow + half * 128;
#pragma unroll
      for (int it = 0; it < 32; ++it) {
        int idx = it * 512 + tid;               // 0..16383
        int k2 = idx & 7;
        int d = (idx >> 3) & 127;
        int tl = (idx >> 10) & 7;
        int hl = idx >> 13;
        u32 lo = eph[(tl * 16 + 2 * k2) * 264 + hl * 128 + d];
        u32 hi = eph[(tl * 16 + 2 * k2 + 1) * 264 + hl * 128 + d];
        int tile = (rowbase >> 4) + tl;
        *(u32*)(VT2 + (((size_t)((hh0 + hl) * 256 + tile) * 128 + d) * 16 + 2 * k2)) =
            lo | (hi << 16);
      }
    }
  }
}

// ---------- Wo GEMM: proven 128x128 2-barrier structure, f32 out ----------
__launch_bounds__(256, 2)
__global__ void gemm128_wo_kernel(const u16* __restrict__ A, const u16* __restrict__ Bt,
                                  float* __restrict__ C, int M, int N, int K) {
  __shared__ __align__(16) u16 As[128 * 64];
  __shared__ __align__(16) u16 Bs[128 * 64];
  const int tid  = threadIdx.x;
  const int lane = tid & 63;
  const int wave = tid >> 6;
  const int wr = wave >> 1, wc = wave & 1;
  const int g = lane >> 4, c = lane & 15;
  const int brow = blockIdx.y * 128;
  const int bcol = blockIdx.x * 128;

  int a_goff[4], b_goff[4], l_off[4];
#pragma unroll
  for (int i = 0; i < 4; ++i) {
    int p = (wave * 4 + i) * 1024 + lane * 16;
    int row = p >> 7;
    int colb = (p & 127) ^ ((row & 7) << 4);
    a_goff[i] = (brow + row) * K + (colb >> 1);
    b_goff[i] = (bcol + row) * K + (colb >> 1);
    l_off[i] = p;
  }

  f32x4 acc[4][4];
#pragma unroll
  for (int m = 0; m < 4; ++m)
#pragma unroll
    for (int n = 0; n < 4; ++n) acc[m][n] = (f32x4){0.f, 0.f, 0.f, 0.f};

  for (int k0 = 0; k0 < K; k0 += 64) {
#pragma unroll
    for (int i = 0; i < 4; ++i) {
      async16(A + a_goff[i] + k0, (char*)As + l_off[i]);
      async16(Bt + b_goff[i] + k0, (char*)Bs + l_off[i]);
    }
    __syncthreads();
#pragma unroll
    for (int kk = 0; kk < 2; ++kk) {
      bf16x8 af[4], bfr[4];
#pragma unroll
      for (int m = 0; m < 4; ++m) {
        int row = wr * 64 + m * 16 + c;
        int byte = (row << 7) + ((kk * 64 + (g << 4)) ^ ((row & 7) << 4));
        af[m] = *(const bf16x8*)((const char*)As + byte);
      }
#pragma unroll
      for (int n = 0; n < 4; ++n) {
        int row = wc * 64 + n * 16 + c;
        int byte = (row << 7) + ((kk * 64 + (g << 4)) ^ ((row & 7) << 4));
        bfr[n] = *(const bf16x8*)((const char*)Bs + byte);
      }
#pragma unroll
      for (int m = 0; m < 4; ++m)
#pragma unroll
        for (int n = 0; n < 4; ++n)
          acc[m][n] = __builtin_amdgcn_mfma_f32_16x16x32_bf16(af[m], bfr[n], acc[m][n], 0, 0, 0);
    }
    __syncthreads();
  }

  const int r0 = brow + wr * 64;
  const int c0 = bcol + wc * 64;
#pragma unroll
  for (int m = 0; m < 4; ++m)
#pragma unroll
    for (int n = 0; n < 4; ++n)
#pragma unroll
      for (int r = 0; r < 4; ++r) {
        int rr = r0 + m * 16 + g * 4 + r;
        int cc = c0 + n * 16 + c;
        C[(size_t)rr * N + cc] = acc[m][n][r];
      }
}

// ---------- sparse tile attention: one block per (tile t, head h) ----------
// Proven r12 config: 17 key tiles padded to 20; 272 keys padded to 288.
// Q pre-rotated (S,2048). K from Kp [h][s][128]; V from VT2 [h][tile][d][16].
// bf16 softmax weights overlay the f32 logits buffer row-aligned. LDS 18.7KB.
__launch_bounds__(256, 6)
__global__ void attn_kernel(const u16* __restrict__ Q, const u16* __restrict__ Kp,
                            const u16* __restrict__ VT2, const int* __restrict__ anchors,
                            u16* __restrict__ Out) {
  const int t = blockIdx.x;   // 0..255
  const int h = blockIdx.y;   // 0..15
  __shared__ int tiles[20];
  __shared__ __align__(16) float lg[16][292];    // logits; weights overlay per-row
  const int tid  = threadIdx.x;
  const int lane = tid & 63;
  const int wave = tid >> 6;
  const int g = lane >> 4;          // k-group 0..3
  const int c = lane & 15;

  if (tid < 16) tiles[tid] = anchors[(size_t)((h << 12) + (t * 16 + 15)) * 16 + tid];
  if (tid == 16) tiles[16] = t;            // local tile (order: anchors then local)
  if (tid >= 17 && tid < 20) tiles[tid] = 0;   // dummy tiles (results discarded)
  __syncthreads();

  // ---- QK: Q(16x128) . K_tile(16x128)^T; 5 fixed iters/wave, 1-ahead prefetch
  {
    const u16* qbase = Q + (size_t)(t * 16 + c) * 2048 + h * 128 + g * 8;
    bf16x8 qf[4];
#pragma unroll
    for (int ks = 0; ks < 4; ++ks) qf[ks] = *(const bf16x8*)(qbase + ks * 32);

    int tok_[5];
    const u16* kb_[5];
#pragma unroll
    for (int i = 0; i < 5; ++i) {
      int j = wave + 4 * i;                  // < 20
      tok_[i] = tiles[j] * 16 + c;
      kb_[i] = Kp + ((size_t)h * 4096 + tok_[i]) * 128 + g * 8;
    }
    bf16x8 kfp[2][4];
#pragma unroll
    for (int ks = 0; ks < 4; ++ks) kfp[0][ks] = *(const bf16x8*)(kb_[0] + ks * 32);
#pragma unroll
    for (int i = 0; i < 5; ++i) {
      if (i < 4) {
#pragma unroll
        for (int ks = 0; ks < 4; ++ks)
          kfp[(i + 1) & 1][ks] = *(const bf16x8*)(kb_[i + 1] + ks * 32);
      }
      f32x4 a = (f32x4){0.f, 0.f, 0.f, 0.f};
#pragma unroll
      for (int ks = 0; ks < 4; ++ks)
        a = __builtin_amdgcn_mfma_f32_16x16x32_bf16(qf[ks], kfp[i & 1][ks], a, 0, 0, 0);
      int j = wave + 4 * i;
      if (j < 17) {
#pragma unroll
        for (int r = 0; r < 4; ++r) {
          int qrow = g * 4 + r;
          float vv = a[r] * 0.088388347648318447f;   // 1/sqrt(128)
          if (tok_[i] > t * 16 + qrow) vv = -1e10f;  // future mask
          lg[qrow][j * 16 + c] = vv;
        }
      }
    }
  }
  __syncthreads();

  // ---- softmax per q row: row r handled by 16 threads (col = tid&15)
  {
    const int r = tid >> 4, cc = tid & 15;
    float vals[17];
    float mx = -3.0e38f;
#pragma unroll
    for (int i = 0; i < 17; ++i) { vals[i] = lg[r][i * 16 + cc]; mx = fmaxf(mx, vals[i]); }
#pragma unroll
    for (int d = 1; d < 16; d <<= 1) mx = fmaxf(mx, __shfl_xor(mx, d, 64));
    float sum = 0.f;
#pragma unroll
    for (int i = 0; i < 17; ++i) { vals[i] = __expf(vals[i] - mx); sum += vals[i]; }
#pragma unroll
    for (int d = 1; d < 16; d <<= 1) sum += __shfl_xor(sum, d, 64);
    float inv = sum > 0.f ? 1.0f / sum : 0.f;
    u16* wrow = (u16*)&lg[r][0];
#pragma unroll
    for (int i = 0; i < 17; ++i) wrow[i * 16 + cc] = f2bf(vals[i] * inv);
    wrow[272 + cc] = 0;                        // zero the pad tile's weights
  }
  __syncthreads();

  // ---- PV: out(16x288 . 288x128); wave owns 32 dims; 1-ahead B-pair prefetch
  {
    f32x4 o0 = (f32x4){0.f, 0.f, 0.f, 0.f}, o1 = o0;
    const int d0 = wave * 32;
    const size_t hb = (size_t)h * 256;
    const int keyin = (g & 1) * 8;
    const u16* wrow = (const u16*)&lg[c][0];
    const u16* vb_[9];
#pragma unroll
    for (int ks = 0; ks < 9; ++ks) vb_[ks] = VT2 + (hb + tiles[2 * ks + (g >> 1)]) * 2048;
    bf16x8 pb0[2], pb1[2];
    pb0[0] = *(const bf16x8*)(vb_[0] + (d0 + c) * 16 + keyin);
    pb1[0] = *(const bf16x8*)(vb_[0] + (d0 + 16 + c) * 16 + keyin);
#pragma unroll
    for (int ks = 0; ks < 9; ++ks) {
      if (ks < 8) {
        pb0[(ks + 1) & 1] = *(const bf16x8*)(vb_[ks + 1] + (d0 + c) * 16 + keyin);
        pb1[(ks + 1) & 1] = *(const bf16x8*)(vb_[ks + 1] + (d0 + 16 + c) * 16 + keyin);
      }
      bf16x8 af = *(const bf16x8*)(wrow + ks * 32 + g * 8);
      o0 = __builtin_amdgcn_mfma_f32_16x16x32_bf16(af, pb0[ks & 1], o0, 0, 0, 0);
      o1 = __builtin_amdgcn_mfma_f32_16x16x32_bf16(af, pb1[ks & 1], o1, 0, 0, 0);
    }
#pragma unroll
    for (int r = 0; r < 4; ++r) {
      int qrow = g * 4 + r;
      size_t base = (size_t)(t * 16 + qrow) * 2048 + h * 128;
      Out[base + d0 + c]      = f2bf(o0[r]);
      Out[base + d0 + 16 + c] = f2bf(o1[r]);
    }
  }
}

extern "C" void kernel_launch(void* const* d_in, const int* in_sizes, int n_in,
                              void* d_out, int out_size, void* d_ws, size_t ws_size,
                              hipStream_t stream) {
  (void)in_sizes; (void)n_in; (void)out_size; (void)ws_size;
  const float* x      = (const float*)d_in[0];
  const float* Wq     = (const float*)d_in[1];
  const float* Wk     = (const float*)d_in[2];
  const float* Wv     = (const float*)d_in[3];
  const float* Wo     = (const float*)d_in[4];
  const float* freqs  = (const float*)d_in[5];
  const int* anchors  = (const int*)d_in[6];
  float* out = (float*)d_out;

  char* ws = (char*)d_ws;
  const size_t MB = 1024 * 1024;
  // Layout (98 MB used):
  //  0..16  : xbf, later attnb (x dead after QKV GEMM)
  // 16..40  : wqkvT contiguous (live through QKV GEMM)
  // 40..48  : woT (live until final GEMM)
  // 48..64  : qbf (rotated, written by QKV epilogue)
  // 64..80  : Kp  (head-major rotated k, written by QKV epilogue)
  // 80..96  : VT2 (transposed v, written by QKV epilogue)
  // 96..98  : ct, st
  u16* xbf   = (u16*)(ws + 0);
  u16* wqkvT = (u16*)(ws + 16 * MB);   // (6144 x 2048) bf16, N x K
  u16* woT   = (u16*)(ws + 40 * MB);
  u16* qbf   = (u16*)(ws + 48 * MB);
  u16* Kp    = (u16*)(ws + 64 * MB);
  u16* VT2   = (u16*)(ws + 80 * MB);
  u16* attnb = (u16*)(ws + 0);
  float* ct  = (float*)(ws + 96 * MB);
  float* st  = (float*)(ws + 97 * MB);

  // prep1: weight transposes + x cast + trig table (one launch)
  prep1_kernel<<<17408, 256, 0, stream>>>(x, Wq, Wk, Wv, Wo, freqs,
                                          xbf, wqkvT, woT, ct, st);
  // fused QKV projection (8-phase 256^2, corrected schedule) + rope/repack epilogue
  gemm256_qkv_kernel<<<dim3(24, 16), 512, 0, stream>>>(xbf, wqkvT, qbf, Kp, VT2, ct, st);
  attn_kernel<<<dim3(256, 16), 256, 0, stream>>>(qbf, Kp, VT2, anchors, attnb);
  gemm128_wo_kernel<<<dim3(16, 32), 256, 0, stream>>>(attnb, woT, out, 4096, 2048, 2048);
}

// Round 15
// 226.101 us; speedup vs baseline: 1.0520x; 1.0520x over previous
//
#include <hip/hip_runtime.h>

typedef unsigned short u16;
typedef unsigned int u32;
typedef __attribute__((ext_vector_type(8))) short bf16x8;   // 8 bf16 in 4 VGPRs
typedef __attribute__((ext_vector_type(4))) float f32x4;

// ---------- bf16 helpers (RNE) ----------
__device__ __forceinline__ u16 f2bf(float f) {
  union { float f; u32 u; } v; v.f = f;
  u32 u = v.u;
  return (u16)((u + 0x7FFFu + ((u >> 16) & 1u)) >> 16);
}
__device__ __forceinline__ float bf2f(u16 s) {
  union { u32 u; float f; } v; v.u = ((u32)s) << 16;
  return v.f;
}

// ---------- async global->LDS (16B per lane) ----------
__device__ __forceinline__ void async16(const void* g, void* l) {
  __builtin_amdgcn_global_load_lds(
      (__attribute__((address_space(1))) void*)g,
      (__attribute__((address_space(3))) void*)l, 16, 0, 0);
}

// ---------- prep1: fused {4x weight transpose+cast, x cast, trig table} ----------
__global__ void prep1_kernel(const float* __restrict__ x,
                             const float* __restrict__ W0, const float* __restrict__ W1,
                             const float* __restrict__ W2, const float* __restrict__ W3,
                             const float* __restrict__ freqs,
                             u16* __restrict__ xbf, u16* __restrict__ wqkvT,
                             u16* __restrict__ woT,
                             float* __restrict__ ct, float* __restrict__ st) {
  __shared__ float tile[32][33];
  const int bid = blockIdx.x;
  const int tid = threadIdx.x;
  if (bid < 16384) {
    const int z = bid >> 12;
    const float* in = z == 0 ? W0 : z == 1 ? W1 : z == 2 ? W2 : W3;
    u16* out = z == 3 ? woT : wqkvT + (size_t)z * 4194304;
    const int local = bid & 4095;
    const int c0 = (local & 63) * 32, r0 = (local >> 6) * 32;
    const int tx = tid & 31, ty = tid >> 5;
#pragma unroll
    for (int i = ty; i < 32; i += 8) tile[i][tx] = in[(size_t)(r0 + i) * 2048 + c0 + tx];
    __syncthreads();
    const int cx = tid & 15, iy = tid >> 4;
#pragma unroll
    for (int i = iy; i < 32; i += 16) {
      u32 v = (u32)f2bf(tile[2 * cx][i]) | ((u32)f2bf(tile[2 * cx + 1][i]) << 16);
      *(u32*)(out + (size_t)(c0 + i) * 2048 + r0 + 2 * cx) = v;
    }
  } else if (bid < 24576) {
    int i = (bid - 16384) * 256 + tid;     // < 2097152
    float4 v = ((const float4*)x)[i];
    ushort4 o;
    o.x = f2bf(v.x); o.y = f2bf(v.y); o.z = f2bf(v.z); o.w = f2bf(v.w);
    ((ushort4*)xbf)[i] = o;
  } else {
    int i = (bid - 24576) * 256 + tid;     // < 262144
    float f = freqs[i];
    ct[i] = cosf(f); st[i] = sinf(f);
  }
}

// ---------- bf16 GEMM: C(MxN) = A(MxK) * Bt(NxK)^T, f32 accumulate ----------
// K-loop: proven 97us structure (128x128 tile, BK=64, 4 waves 2x2, single-buffer
// LDS, two __syncthreads per K-tile, zero bank conflicts).
// Fragment columns remapped so n and n+2 are 64 dims apart:
//   col(n) = (n&2)*32 + wc*32 + (n&1)*16 + c   -> RoPE pair (d, d+64) is
// thread-local (acc[m][n], acc[m][n+2]).
// MODE 0: plain f32 out (Wo). MODE 2: QKV-fused epilogue -- q/k rotated fully
// in-register (no LDS, no barriers); v transposed via padded LDS bounce.
template <int MODE>
__launch_bounds__(256, 2)
__global__ void gemm128_kernel(const u16* __restrict__ A, const u16* __restrict__ Bt,
                               void* __restrict__ C, u16* __restrict__ D1, u16* __restrict__ D2,
                               const float* __restrict__ ct, const float* __restrict__ st,
                               int M, int N, int K) {
  __shared__ __align__(16) char smem[33152];   // K-loop: As(16K)+Bs(16K); v-epilogue: f32[64][129]
  u16* As = (u16*)smem;
  u16* Bs = (u16*)(smem + 16384);
  const int tid  = threadIdx.x;
  const int lane = tid & 63;
  const int wave = tid >> 6;
  const int wr = wave >> 1, wc = wave & 1;
  const int g = lane >> 4, c = lane & 15;
  const int brow = blockIdx.y * 128;
  const int bcol = blockIdx.x * 128;

  int a_goff[4], b_goff[4], l_off[4];
#pragma unroll
  for (int i = 0; i < 4; ++i) {
    int p = (wave * 4 + i) * 1024 + lane * 16;        // linear byte in 16KB tile
    int row = p >> 7;                                 // 128B per row (64 bf16)
    int colb = (p & 127) ^ ((row & 7) << 4);          // inverse swizzle on source
    a_goff[i] = (brow + row) * K + (colb >> 1);
    b_goff[i] = (bcol + row) * K + (colb >> 1);
    l_off[i] = p;
  }

  f32x4 acc[4][4];
#pragma unroll
  for (int m = 0; m < 4; ++m)
#pragma unroll
    for (int n = 0; n < 4; ++n) acc[m][n] = (f32x4){0.f, 0.f, 0.f, 0.f};

  for (int k0 = 0; k0 < K; k0 += 64) {
#pragma unroll
    for (int i = 0; i < 4; ++i) {
      async16(A + a_goff[i] + k0, (char*)As + l_off[i]);
      async16(Bt + b_goff[i] + k0, (char*)Bs + l_off[i]);
    }
    __syncthreads();
#pragma unroll
    for (int kk = 0; kk < 2; ++kk) {
      bf16x8 af[4], bfr[4];
#pragma unroll
      for (int m = 0; m < 4; ++m) {
        int row = wr * 64 + m * 16 + c;
        int byte = (row << 7) + ((kk * 64 + (g << 4)) ^ ((row & 7) << 4));
        af[m] = *(const bf16x8*)((const char*)As + byte);
      }
#pragma unroll
      for (int n = 0; n < 4; ++n) {
        int row = ((n & 2) << 5) + wc * 32 + ((n & 1) << 4) + c;   // remapped col
        int byte = (row << 7) + ((kk * 64 + (g << 4)) ^ ((row & 7) << 4));
        bfr[n] = *(const bf16x8*)((const char*)Bs + byte);
      }
#pragma unroll
      for (int m = 0; m < 4; ++m)
#pragma unroll
        for (int n = 0; n < 4; ++n)
          acc[m][n] = __builtin_amdgcn_mfma_f32_16x16x32_bf16(af[m], bfr[n], acc[m][n], 0, 0, 0);
    }
    __syncthreads();
  }

  if (MODE == 2) {
    const int sel = bcol >> 11;                       // 0=q 1=k 2=v (block-uniform)
    const int hh  = (bcol & 2047) >> 7;               // head index
    if (sel < 2) {
      // ---- q/k: in-register RoPE; pair = (acc[m][n], acc[m][n+2]) ----
#pragma unroll
      for (int m = 0; m < 4; ++m)
#pragma unroll
        for (int r = 0; r < 4; ++r) {
          const int t = brow + wr * 64 + m * 16 + g * 4 + r;
          const int tb = t * 64;
#pragma unroll
          for (int n = 0; n < 2; ++n) {
            const int d = wc * 32 + (n << 4) + c;     // 0..63
            float cv = ct[tb + d], sv = st[tb + d];
            float a = acc[m][n][r], b = acc[m][n + 2][r];
            u16 lo = f2bf(a * cv - b * sv);
            u16 hi = f2bf(b * cv + a * sv);
            if (sel == 0) {
              u16* qd = (u16*)C + (size_t)t * 2048 + hh * 128 + d;
              qd[0] = lo; qd[64] = hi;
            } else {
              u16* kd = D1 + ((size_t)hh * 4096 + t) * 128 + d;
              kd[0] = lo; kd[64] = hi;
            }
          }
        }
    } else {
      // ---- v: transpose via padded LDS bounce -> VT2[h][tile][d][16] ----
      float* ep = (float*)smem;                       // [64][129]
#pragma unroll
      for (int half = 0; half < 2; ++half) {
        if (wr == half) {
#pragma unroll
          for (int m = 0; m < 4; ++m)
#pragma unroll
            for (int n = 0; n < 4; ++n)
#pragma unroll
              for (int r = 0; r < 4; ++r) {
                int lr = m * 16 + g * 4 + r;                          // 0..63
                int lc = ((n & 2) << 5) + wc * 32 + ((n & 1) << 4) + c;
                ep[lr * 129 + lc] = acc[m][n][r];
              }
        }
        __syncthreads();
        const int rowbase = brow + half * 64;
#pragma unroll
        for (int it = 0; it < 16; ++it) {
          int idx = it * 256 + tid;          // 0..4095
          int tl = idx >> 10;                // local tile 0..3
          int d  = (idx >> 3) & 127;
          int k2 = idx & 7;                  // u32 over 2 keys
          u32 lo = f2bf(ep[(tl * 16 + 2 * k2) * 129 + d]);
          u32 hi = f2bf(ep[(tl * 16 + 2 * k2 + 1) * 129 + d]);
          int tile = (rowbase >> 4) + tl;
          *(u32*)(D2 + (((size_t)(hh * 256 + tile) * 128 + d) * 16 + 2 * k2)) = lo | (hi << 16);
        }
        __syncthreads();
      }
    }
  } else {
    const int r0 = brow + wr * 64;
#pragma unroll
    for (int m = 0; m < 4; ++m)
#pragma unroll
      for (int n = 0; n < 4; ++n)
#pragma unroll
        for (int r = 0; r < 4; ++r) {
          int rr = r0 + m * 16 + g * 4 + r;
          int cc = bcol + ((n & 2) << 5) + wc * 32 + ((n & 1) << 4) + c;
          ((float*)C)[(size_t)rr * N + cc] = acc[m][n][r];
        }
  }
}

// ---------- sparse tile attention: one block per (tile t, head h) ----------
// 17 key tiles (16 anchors + local) padded to 20; 272 keys padded to 288 with
// zero weights. Q pre-rotated (S,2048). K from Kp [h][s][128]; V from VT2
// [h][tile][d][16]. bf16 softmax weights overlay the f32 logits buffer
// row-aligned (1168B rows: PV start-banks 2-way aliased = free). LDS 18.7KB.
__launch_bounds__(256, 6)
__global__ void attn_kernel(const u16* __restrict__ Q, const u16* __restrict__ Kp,
                            const u16* __restrict__ VT2, const int* __restrict__ anchors,
                            u16* __restrict__ Out) {
  const int t = blockIdx.x;   // 0..255
  const int h = blockIdx.y;   // 0..15
  __shared__ int tiles[20];
  __shared__ __align__(16) float lg[16][292];    // logits; weights overlay per-row
  const int tid  = threadIdx.x;
  const int lane = tid & 63;
  const int wave = tid >> 6;
  const int g = lane >> 4;          // k-group 0..3
  const int c = lane & 15;

  if (tid < 16) tiles[tid] = anchors[(size_t)((h << 12) + (t * 16 + 15)) * 16 + tid];
  if (tid == 16) tiles[16] = t;            // local tile (order: anchors then local)
  if (tid >= 17 && tid < 20) tiles[tid] = 0;   // dummy tiles (results discarded)
  __syncthreads();

  // ---- QK: Q(16x128) . K_tile(16x128)^T; 5 fixed iters/wave, 1-ahead prefetch
  {
    const u16* qbase = Q + (size_t)(t * 16 + c) * 2048 + h * 128 + g * 8;
    bf16x8 qf[4];
#pragma unroll
    for (int ks = 0; ks < 4; ++ks) qf[ks] = *(const bf16x8*)(qbase + ks * 32);

    int tok_[5];
    const u16* kb_[5];
#pragma unroll
    for (int i = 0; i < 5; ++i) {
      int j = wave + 4 * i;                  // < 20
      tok_[i] = tiles[j] * 16 + c;
      kb_[i] = Kp + ((size_t)h * 4096 + tok_[i]) * 128 + g * 8;
    }
    bf16x8 kfp[2][4];
#pragma unroll
    for (int ks = 0; ks < 4; ++ks) kfp[0][ks] = *(const bf16x8*)(kb_[0] + ks * 32);
#pragma unroll
    for (int i = 0; i < 5; ++i) {
      if (i < 4) {
#pragma unroll
        for (int ks = 0; ks < 4; ++ks)
          kfp[(i + 1) & 1][ks] = *(const bf16x8*)(kb_[i + 1] + ks * 32);
      }
      f32x4 a = (f32x4){0.f, 0.f, 0.f, 0.f};
#pragma unroll
      for (int ks = 0; ks < 4; ++ks)
        a = __builtin_amdgcn_mfma_f32_16x16x32_bf16(qf[ks], kfp[i & 1][ks], a, 0, 0, 0);
      int j = wave + 4 * i;
      if (j < 17) {
#pragma unroll
        for (int r = 0; r < 4; ++r) {
          int qrow = g * 4 + r;
          float vv = a[r] * 0.088388347648318447f;   // 1/sqrt(128)
          if (tok_[i] > t * 16 + qrow) vv = -1e10f;  // future mask
          lg[qrow][j * 16 + c] = vv;
        }
      }
    }
  }
  __syncthreads();

  // ---- softmax per q row: row r handled by 16 threads (col = tid&15)
  {
    const int r = tid >> 4, cc = tid & 15;
    float vals[17];
    float mx = -3.0e38f;
#pragma unroll
    for (int i = 0; i < 17; ++i) { vals[i] = lg[r][i * 16 + cc]; mx = fmaxf(mx, vals[i]); }
#pragma unroll
    for (int d = 1; d < 16; d <<= 1) mx = fmaxf(mx, __shfl_xor(mx, d, 64));
    float sum = 0.f;
#pragma unroll
    for (int i = 0; i < 17; ++i) { vals[i] = __expf(vals[i] - mx); sum += vals[i]; }
#pragma unroll
    for (int d = 1; d < 16; d <<= 1) sum += __shfl_xor(sum, d, 64);
    float inv = sum > 0.f ? 1.0f / sum : 0.f;
    u16* wrow = (u16*)&lg[r][0];
#pragma unroll
    for (int i = 0; i < 17; ++i) wrow[i * 16 + cc] = f2bf(vals[i] * inv);
    wrow[272 + cc] = 0;                        // zero the pad tile's weights
  }
  __syncthreads();

  // ---- PV: out(16x288 . 288x128); wave owns 32 dims; 1-ahead B-pair prefetch
  {
    f32x4 o0 = (f32x4){0.f, 0.f, 0.f, 0.f}, o1 = o0;
    const int d0 = wave * 32;
    const size_t hb = (size_t)h * 256;
    const int keyin = (g & 1) * 8;
    const u16* wrow = (const u16*)&lg[c][0];
    const u16* vb_[9];
#pragma unroll
    for (int ks = 0; ks < 9; ++ks) vb_[ks] = VT2 + (hb + tiles[2 * ks + (g >> 1)]) * 2048;
    bf16x8 pb0[2], pb1[2];
    pb0[0] = *(const bf16x8*)(vb_[0] + (d0 + c) * 16 + keyin);
    pb1[0] = *(const bf16x8*)(vb_[0] + (d0 + 16 + c) * 16 + keyin);
#pragma unroll
    for (int ks = 0; ks < 9; ++ks) {
      if (ks < 8) {
        pb0[(ks + 1) & 1] = *(const bf16x8*)(vb_[ks + 1] + (d0 + c) * 16 + keyin);
        pb1[(ks + 1) & 1] = *(const bf16x8*)(vb_[ks + 1] + (d0 + 16 + c) * 16 + keyin);
      }
      bf16x8 af = *(const bf16x8*)(wrow + ks * 32 + g * 8);
      o0 = __builtin_amdgcn_mfma_f32_16x16x32_bf16(af, pb0[ks & 1], o0, 0, 0, 0);
      o1 = __builtin_amdgcn_mfma_f32_16x16x32_bf16(af, pb1[ks & 1], o1, 0, 0, 0);
    }
#pragma unroll
    for (int r = 0; r < 4; ++r) {
      int qrow = g * 4 + r;
      size_t base = (size_t)(t * 16 + qrow) * 2048 + h * 128;
      Out[base + d0 + c]      = f2bf(o0[r]);
      Out[base + d0 + 16 + c] = f2bf(o1[r]);
    }
  }
}

extern "C" void kernel_launch(void* const* d_in, const int* in_sizes, int n_in,
                              void* d_out, int out_size, void* d_ws, size_t ws_size,
                              hipStream_t stream) {
  (void)in_sizes; (void)n_in; (void)out_size; (void)ws_size;
  const float* x      = (const float*)d_in[0];
  const float* Wq     = (const float*)d_in[1];
  const float* Wk     = (const float*)d_in[2];
  const float* Wv     = (const float*)d_in[3];
  const float* Wo     = (const float*)d_in[4];
  const float* freqs  = (const float*)d_in[5];
  const int* anchors  = (const int*)d_in[6];
  float* out = (float*)d_out;

  char* ws = (char*)d_ws;
  const size_t MB = 1024 * 1024;
  // Layout (98 MB used):
  //  0..16  : xbf, later attnb (x dead after QKV GEMM)
  // 16..40  : wqkvT contiguous (live through QKV GEMM)
  // 40..48  : woT (live until final GEMM)
  // 48..64  : qbf (rotated, written by QKV epilogue)
  // 64..80  : Kp  (head-major rotated k, written by QKV epilogue)
  // 80..96  : VT2 (transposed v, written by QKV epilogue)
  // 96..98  : ct, st
  u16* xbf   = (u16*)(ws + 0);
  u16* wqkvT = (u16*)(ws + 16 * MB);   // (6144 x 2048) bf16, N x K
  u16* woT   = (u16*)(ws + 40 * MB);
  u16* qbf   = (u16*)(ws + 48 * MB);
  u16* Kp    = (u16*)(ws + 64 * MB);
  u16* VT2   = (u16*)(ws + 80 * MB);
  u16* attnb = (u16*)(ws + 0);
  float* ct  = (float*)(ws + 96 * MB);
  float* st  = (float*)(ws + 97 * MB);

  // prep1: weight transposes + x cast + trig table (one launch)
  prep1_kernel<<<25600, 256, 0, stream>>>(x, Wq, Wk, Wv, Wo, freqs,
                                          xbf, wqkvT, woT, ct, st);
  // fused QKV projection + rope/repack epilogue
  gemm128_kernel<2><<<dim3(48, 32), 256, 0, stream>>>(xbf, wqkvT, qbf, Kp, VT2,
                                                      ct, st, 4096, 6144, 2048);
  attn_kernel<<<dim3(256, 16), 256, 0, stream>>>(qbf, Kp, VT2, anchors, attnb);
  gemm128_kernel<0><<<dim3(16, 32), 256, 0, stream>>>(attnb, woT, out, nullptr, nullptr,
                                                      nullptr, nullptr, 4096, 2048, 2048);
}